// Round 8
// baseline (151.082 us; speedup 1.0000x reference)
//
#include <hip/hip_runtime.h>
#include <math.h>
#include <stdint.h>

// Video Swin shifted-window attention, fully fused, one block per window.
// Round 8: phase-2 rewritten on 32x32x16 MFMA (T12 pattern):
//  - 16 tasks (4 heads x 4 i-tiles of 32) == 16 waves, single pass
//  - softmax j-axis fully lane-local: in-lane tree + ONE shfl_xor(32)
//  - P stays in registers: cvt_pk pack + v_permlane32_swap_b32 pairs build
//    the PV B-fragments in place; p_lds deleted (LDS 156KB -> 123KB)
//  - bias table bm3 in fragment-gathered layout: coalesced f32x4 -> C-operand
//  - unified swz2 adds ((row>>3)&3) entropy (32-row fragment reads 2-way)

#define LOG2E   1.4426950408889634f
#define MASKNEG (-144.26950408889634f)   // -100 * LOG2E

typedef __attribute__((ext_vector_type(8)))  short    bf16x8;
typedef __attribute__((ext_vector_type(4)))  float    f32x4;
typedef __attribute__((ext_vector_type(16))) float    f32x16;
typedef __attribute__((ext_vector_type(4)))  unsigned uint32x4;

__device__ __forceinline__ unsigned short cvt1(float f) {
    __bf16 h = (__bf16)f;
    return __builtin_bit_cast(unsigned short, h);
}
__device__ __forceinline__ unsigned cvt2(float lo, float hi) {
    return (unsigned)cvt1(lo) | ((unsigned)cvt1(hi) << 16);
}

// v_permlane32_swap_b32 a, b:  a[32+i] <-> b[i]
// after: a = {a_lo | b_lo(from partner)}, b = {a_hi(from partner) | b_hi}
__device__ __forceinline__ void pswap(unsigned &a, unsigned &b) {
    asm volatile("v_permlane32_swap_b32 %0, %1" : "+v"(a), "+v"(b));
}

// token region code for the shifted-window mask (WIN=(2,7,7), SHIFT=(1,3,3))
__device__ __forceinline__ int tok_code(int t) {
    int pd = t / 49;
    int r  = t - pd * 49;
    int ph = r / 7;
    int pw = r - ph * 7;
    return (pd >= 1 ? 1 : 0) | (ph >= 4 ? 2 : 0) | (pw >= 4 ? 4 : 0);
}

// XOR-swizzled element offset in [rows][128]-bf16 tiles (16B chunks).
// Entropy from row bits [2:0] AND [3:2] so both 16-row and 32-row
// per-lane fragment reads stay <=2-way.
__device__ __forceinline__ int swz2(int row, int col) {
    return row * 128 + ((((col >> 3) ^ (row & 7) ^ ((row >> 3) & 3)) & 15) << 3) + (col & 7);
}

// ---------------- prep: weights -> bf16, bias tables ----------------
// BIG  : bm3 f32 [cls8][h4][it4][jt4][q4][hi2][il32][e4]  (2MB)
// small: bm3s bf16 [h4][it4][jt4][q4][hi2][il32][e4]      (128KB), mask in-kernel
template<bool BIG>
__global__ void prep_kernel(const float* __restrict__ qkv_w,
                            const float* __restrict__ proj_w,
                            const float* __restrict__ rpb_table,
                            const int*   __restrict__ rel_index,
                            unsigned short* __restrict__ wqkv,
                            unsigned short* __restrict__ wproj,
                            void* __restrict__ btab) {
    int tid = blockIdx.x * blockDim.x + threadIdx.x;
    int stride = gridDim.x * blockDim.x;
    for (int i = tid; i < 384 * 128; i += stride) wqkv[i]  = cvt1(qkv_w[i]);
    for (int i = tid; i < 128 * 128; i += stride) wproj[i] = cvt1(proj_w[i]);
    if constexpr (BIG) {
        float* bm = (float*)btab;
        for (int idx = tid; idx < 524288; idx += stride) {
            int e  = idx & 3;
            int il = (idx >> 2) & 31;
            int hi = (idx >> 7) & 1;
            int q  = (idx >> 8) & 3;
            int jt = (idx >> 10) & 3;
            int it = (idx >> 12) & 3;
            int h  = (idx >> 14) & 3;
            int cl = (idx >> 16);
            int i = it * 32 + il;
            int j = jt * 32 + q * 8 + hi * 4 + e;
            float v;
            if (j >= 98) v = -INFINITY;
            else if (i >= 98) v = 0.f;
            else {
                float bias = rpb_table[rel_index[i * 98 + j] * 4 + h];
                bool  msk  = (((unsigned)tok_code(i) ^ (unsigned)tok_code(j)) & (unsigned)cl) != 0;
                v = bias * LOG2E + (msk ? MASKNEG : 0.f);
            }
            bm[idx] = v;
        }
    } else {
        unsigned short* bm = (unsigned short*)btab;
        for (int idx = tid; idx < 65536; idx += stride) {
            int e  = idx & 3;
            int il = (idx >> 2) & 31;
            int hi = (idx >> 7) & 1;
            int q  = (idx >> 8) & 3;
            int jt = (idx >> 10) & 3;
            int it = (idx >> 12) & 3;
            int h  = (idx >> 14) & 3;
            int i = it * 32 + il;
            int j = jt * 32 + q * 8 + hi * 4 + e;
            float v;
            if (j >= 98) v = -INFINITY;
            else if (i >= 98) v = 0.f;
            else v = rpb_table[rel_index[i * 98 + j] * 4 + h] * LOG2E;
            bm[idx] = cvt1(v);
        }
    }
}

// ---------------- main fused kernel ----------------
template<bool BIG>
__global__ __launch_bounds__(1024)
void swin_main(const float* __restrict__ x,
               const float* __restrict__ qkv_b,
               const float* __restrict__ proj_b,
               const unsigned short* __restrict__ wqkv,
               const unsigned short* __restrict__ wproj,
               const void* __restrict__ btab,
               float* __restrict__ out)
{
    extern __shared__ unsigned short lds[];
    unsigned short* q_lds  = lds;            // [112][128] bf16, swz2
    unsigned short* k_lds  = lds + 14336;    // [112][128]
    unsigned short* vT_lds = lds + 28672;    // [128][128] (cols 112..127 zeroed)
    unsigned short* xo_lds = lds + 45056;    // [128][128] x(rows<112) then O(all)
    // total 61440 ushorts = 122880 B

    const int b    = blockIdx.x;
    const int tid  = threadIdx.x;
    const int wv   = tid >> 6;    // 0..15
    const int lane = tid & 63;
    const int l4   = lane >> 4;   // 0..3
    const int lc   = lane & 15;   // 0..15

    // zero vT pad cols 112..127 (stale-LDS inf/nan there would poison 0*x)
    {
        int idx2 = tid * 2;
        int row  = idx2 >> 4;
        int c    = 112 + (idx2 & 15);
        *(unsigned int*)(vT_lds + swz2(row, c)) = 0u;
    }

    // stage x -> xo_lds rows 0..111 as bf16 (98..111 zero)
    {
        const float* xb = x + (size_t)b * 12544;
        for (int idx = tid; idx < 3584; idx += 1024) {
            int tok = idx >> 5;
            int c   = (idx & 31) << 2;
            float4 v;
            if (tok < 98) v = *(const float4*)(xb + tok * 128 + c);
            else { v.x = 0.f; v.y = 0.f; v.z = 0.f; v.w = 0.f; }
            uint2 hv; hv.x = cvt2(v.x, v.y); hv.y = cvt2(v.z, v.w);
            *(uint2*)(xo_lds + swz2(tok, c)) = hv;
        }
    }
    __syncthreads();

    // ---- Phase 1: QKV' = Wqkv @ X^T (unchanged structure, swz2) ----
    {
        const int ct = wv;
        bf16x8 wf[4];
        f32x4  bias;
        const unsigned short* wrow = wqkv + (ct * 16 + lc) * 128;
#pragma unroll
        for (int kt = 0; kt < 4; ++kt) wf[kt] = *(const bf16x8*)(wrow + kt * 32 + l4 * 8);
#pragma unroll
        for (int r = 0; r < 4; ++r) bias[r] = qkv_b[ct * 16 + l4 * 4 + r];
        const bool  isq = (ct < 8);
        const float qs  = 0.17677669529663689f * LOG2E;
#pragma unroll
        for (int t = 0; t < 7; ++t) {
            bf16x8 xf[4];
#pragma unroll
            for (int kt = 0; kt < 4; ++kt)
                xf[kt] = *(bf16x8*)(xo_lds + swz2(t * 16 + lc, kt * 32 + l4 * 8));
            f32x4 acc = bias;
#pragma unroll
            for (int kt = 0; kt < 4; ++kt)
                acc = __builtin_amdgcn_mfma_f32_16x16x32_bf16(wf[kt], xf[kt], acc, 0, 0, 0);
            int tok = t * 16 + lc;
            if (isq) {
                uint2 hv; hv.x = cvt2(acc[0] * qs, acc[1] * qs); hv.y = cvt2(acc[2] * qs, acc[3] * qs);
                *(uint2*)(q_lds + swz2(tok, ct * 16 + l4 * 4)) = hv;
            } else {
                uint2 hv; hv.x = cvt2(acc[0], acc[1]); hv.y = cvt2(acc[2], acc[3]);
                *(uint2*)(k_lds + swz2(tok, (ct - 8) * 16 + l4 * 4)) = hv;
            }
        }
        const int vd = (wv >> 1) * 16;
        bf16x8 wf2[4];
        const unsigned short* wrow2 = wqkv + (256 + vd + lc) * 128;
#pragma unroll
        for (int kt = 0; kt < 4; ++kt) wf2[kt] = *(const bf16x8*)(wrow2 + kt * 32 + l4 * 8);
        f32x4 bias2;
#pragma unroll
        for (int r = 0; r < 4; ++r) bias2[r] = qkv_b[256 + vd + l4 * 4 + r];
        const int t0 = (wv & 1) ? 4 : 0, t1 = (wv & 1) ? 7 : 4;
        for (int t = t0; t < t1; ++t) {
            bf16x8 xf[4];
#pragma unroll
            for (int kt = 0; kt < 4; ++kt)
                xf[kt] = *(bf16x8*)(xo_lds + swz2(t * 16 + lc, kt * 32 + l4 * 8));
            f32x4 acc = bias2;
#pragma unroll
            for (int kt = 0; kt < 4; ++kt)
                acc = __builtin_amdgcn_mfma_f32_16x16x32_bf16(wf2[kt], xf[kt], acc, 0, 0, 0);
            int tok = t * 16 + lc;
            const int rb = vd + l4 * 4;
            vT_lds[swz2(rb + 0, tok)] = cvt1(acc[0]);
            vT_lds[swz2(rb + 1, tok)] = cvt1(acc[1]);
            vT_lds[swz2(rb + 2, tok)] = cvt1(acc[2]);
            vT_lds[swz2(rb + 3, tok)] = cvt1(acc[3]);
        }
    }
    __syncthreads();

    // ---- Phase 2: attention, 32x32 path. wave = (h = wv>>2, itile = wv&3) ----
    const int wi  = b & 255;
    const unsigned int cls =
        ((wi >> 6) == 3 ? 1u : 0u) | (((wi >> 3) & 7) == 7 ? 2u : 0u) | ((wi & 7) == 7 ? 4u : 0u);
    {
        const int il  = lane & 31;
        const int hi2 = lane >> 5;
        const int h     = wv >> 2;
        const int itile = wv & 3;
        const int i_tok = itile * 32 + il;

        // C-operand = bias(+mask) straight from gathered table
        f32x16 S[4];
        if constexpr (BIG) {
            const float* tb = (const float*)btab
                + (((size_t)(cls * 4 + h) * 4 + itile) * 4) * 1024 + hi2 * 128 + il * 4;
#pragma unroll
            for (int jt = 0; jt < 4; ++jt)
#pragma unroll
                for (int q = 0; q < 4; ++q) {
                    f32x4 v = *(const f32x4*)(tb + (jt * 8 + q * 2) * 128);
                    S[jt][q * 4 + 0] = v[0]; S[jt][q * 4 + 1] = v[1];
                    S[jt][q * 4 + 2] = v[2]; S[jt][q * 4 + 3] = v[3];
                }
        } else {
            const unsigned short* tb = (const unsigned short*)btab
                + ((h * 4 + itile) * 4) * 1024 + hi2 * 128 + il * 4;
            const unsigned int ci = (unsigned)tok_code(i_tok);
#pragma unroll
            for (int jt = 0; jt < 4; ++jt)
#pragma unroll
                for (int q = 0; q < 4; ++q) {
                    ushort4 bb = *(const ushort4*)(tb + (jt * 8 + q * 2) * 128);
#pragma unroll
                    for (int e = 0; e < 4; ++e) {
                        unsigned short us = (e == 0) ? bb.x : (e == 1) ? bb.y : (e == 2) ? bb.z : bb.w;
                        int j = jt * 32 + q * 8 + hi2 * 4 + e;
                        float mv = (((unsigned)tok_code(j) ^ ci) & cls) ? MASKNEG : 0.f;
                        S[jt][q * 4 + e] = __builtin_bit_cast(float, (unsigned)us << 16) + mv;
                    }
                }
        }

        // QK^T: S^T[j][i] += K · Q^T   (A rows=j, B cols=i, K=ch 32 in 2 halves)
        bf16x8 qfa = *(bf16x8*)(q_lds + swz2(i_tok, h * 32 + hi2 * 8));
        bf16x8 qfb = *(bf16x8*)(q_lds + swz2(i_tok, h * 32 + 16 + hi2 * 8));
#pragma unroll
        for (int jt = 0; jt < 4; ++jt) {
            bf16x8 ka = *(bf16x8*)(k_lds + swz2(jt * 32 + il, h * 32 + hi2 * 8));
            bf16x8 kb = *(bf16x8*)(k_lds + swz2(jt * 32 + il, h * 32 + 16 + hi2 * 8));
            S[jt] = __builtin_amdgcn_mfma_f32_32x32x16_bf16(ka, qfa, S[jt], 0, 0, 0);
            S[jt] = __builtin_amdgcn_mfma_f32_32x32x16_bf16(kb, qfb, S[jt], 0, 0, 0);
        }

        // softmax over j: 64 in-lane values + partner half via ONE swap
        float m = S[0][0];
#pragma unroll
        for (int jt = 0; jt < 4; ++jt)
#pragma unroll
            for (int r = 0; r < 16; ++r)
                if (!(jt == 0 && r == 0)) m = fmaxf(m, S[jt][r]);
        m = fmaxf(m, __shfl_xor(m, 32));

        float l = 0.f;
        unsigned dw[4][8];
#pragma unroll
        for (int jt = 0; jt < 4; ++jt)
#pragma unroll
            for (int d = 0; d < 8; ++d) {
                float p0 = exp2f(S[jt][2 * d]     - m);
                float p1 = exp2f(S[jt][2 * d + 1] - m);
                l += p0 + p1;
                dw[jt][d] = cvt2(p0, p1);
            }
        l += __shfl_xor(l, 32);

        // in-place permlane32 swaps: [P0,P1,P2,P3] / [P4,P5,P6,P7] become
        // the PV B-fragments for (tile jt, k-half 0/1) on BOTH lane halves
#pragma unroll
        for (int jt = 0; jt < 4; ++jt) {
            pswap(dw[jt][0], dw[jt][2]);
            pswap(dw[jt][1], dw[jt][3]);
            pswap(dw[jt][4], dw[jt][6]);
            pswap(dw[jt][5], dw[jt][7]);
        }

        // PV: O^T[d][i] = V^T · P^T, K = j (8 x 32x32x16)
        f32x16 O = {0.f,0.f,0.f,0.f,0.f,0.f,0.f,0.f,0.f,0.f,0.f,0.f,0.f,0.f,0.f,0.f};
#pragma unroll
        for (int jt = 0; jt < 4; ++jt)
#pragma unroll
            for (int p = 0; p < 2; ++p) {
                bf16x8 vf = *(bf16x8*)(vT_lds + swz2(h * 32 + il, jt * 32 + p * 16 + hi2 * 8));
                uint32x4 pu = { dw[jt][p * 4 + 0], dw[jt][p * 4 + 1],
                                dw[jt][p * 4 + 2], dw[jt][p * 4 + 3] };
                O = __builtin_amdgcn_mfma_f32_32x32x16_bf16(
                        vf, __builtin_bit_cast(bf16x8, pu), O, 0, 0, 0);
            }

        const float inv = 1.0f / l;
#pragma unroll
        for (int rr = 0; rr < 8; ++rr) {
            int r = rr * 2;
            int d = (r & 3) + 8 * (r >> 2) + 4 * hi2;
            *(unsigned*)(xo_lds + swz2(i_tok, h * 32 + d)) = cvt2(O[r] * inv, O[r + 1] * inv);
        }
    }
    __syncthreads();

    // ---- Phase 3: y^T = Wproj @ O^T (unchanged, swz2) ----
    {
        const int ct = wv >> 1;
        bf16x8 pw[4];
#pragma unroll
        for (int kt = 0; kt < 4; ++kt)
            pw[kt] = *(const bf16x8*)(wproj + (ct * 16 + lc) * 128 + kt * 32 + l4 * 8);
        f32x4 pbias;
#pragma unroll
        for (int r = 0; r < 4; ++r) pbias[r] = proj_b[ct * 16 + l4 * 4 + r];

        float* ob = out + (size_t)b * 12544;
        const int t0 = (wv & 1) ? 4 : 0, t1 = (wv & 1) ? 7 : 4;
        for (int t = t0; t < t1; ++t) {
            f32x4 acc = pbias;
#pragma unroll
            for (int kt = 0; kt < 4; ++kt) {
                bf16x8 of = *(bf16x8*)(xo_lds + swz2(t * 16 + lc, kt * 32 + l4 * 8));
                acc = __builtin_amdgcn_mfma_f32_16x16x32_bf16(pw[kt], of, acc, 0, 0, 0);
            }
            int tok = t * 16 + lc;
            if (tok < 98) {
                float4 st; st.x = acc[0]; st.y = acc[1]; st.z = acc[2]; st.w = acc[3];
                *(float4*)(ob + tok * 128 + ct * 16 + l4 * 4) = st;
            }
        }
    }
}

extern "C" void kernel_launch(void* const* d_in, const int* in_sizes, int n_in,
                              void* d_out, int out_size, void* d_ws, size_t ws_size,
                              hipStream_t stream) {
    const float* x       = (const float*)d_in[0];
    const float* qkv_w   = (const float*)d_in[1];
    const float* qkv_b   = (const float*)d_in[2];
    const float* rpb_tab = (const float*)d_in[3];
    const float* proj_w  = (const float*)d_in[4];
    const float* proj_b  = (const float*)d_in[5];
    const int*   rel_idx = (const int*)d_in[6];
    // d_in[7] (mask) unused: reproduced analytically into the tables.

    unsigned short* wqkv  = (unsigned short*)d_ws;                   // 98304 B
    unsigned short* wproj = (unsigned short*)((char*)d_ws + 98304);  // 32768 B
    void*           btab  = (void*)((char*)d_ws + 131072);           // bias table
    float*          out   = (float*)d_out;

    const bool big = ws_size >= (size_t)(131072 + 524288 * 4);  // 2,228,224 B
    const int LDS_BYTES = 122880;

    if (big) {
        hipLaunchKernelGGL((prep_kernel<true>), dim3(512), dim3(256), 0, stream,
                           qkv_w, proj_w, rpb_tab, rel_idx, wqkv, wproj, btab);
        (void)hipFuncSetAttribute((const void*)(swin_main<true>),
                                  hipFuncAttributeMaxDynamicSharedMemorySize, LDS_BYTES);
        hipLaunchKernelGGL((swin_main<true>), dim3(2048), dim3(1024), LDS_BYTES, stream,
                           x, qkv_b, proj_b, wqkv, wproj, btab, out);
    } else {
        hipLaunchKernelGGL((prep_kernel<false>), dim3(512), dim3(256), 0, stream,
                           qkv_w, proj_w, rpb_tab, rel_idx, wqkv, wproj, btab);
        (void)hipFuncSetAttribute((const void*)(swin_main<false>),
                                  hipFuncAttributeMaxDynamicSharedMemorySize, LDS_BYTES);
        hipLaunchKernelGGL((swin_main<false>), dim3(2048), dim3(1024), LDS_BYTES, stream,
                           x, qkv_b, proj_b, wqkv, wproj, btab, out);
    }
}